// Round 13
// baseline (168.214 us; speedup 1.0000x reference)
//
#include <hip/hip_runtime.h>
#include <hip/hip_bf16.h>

#define IN_C  128
#define HID_C 64
#define OUT_C 32
#define NEG_SLOPE 0.2f
#define EPB1    1024     // edges per bin1 block
#define EPB2    2048     // records per bin2 part
#define BUCKETW 64       // dst nodes per region
#define RCAP    1536     // region capacity (mean 1023, +16 sigma)
#define SUPW    1024     // dst nodes per super-bucket
#define RCAP1   18432    // super capacity (mean 16327) = 9*2048
#define PARTS   9        // bin2 parts per super
#define CSTRIDE 16       // cursor padding (64B) to spread atomic lines

typedef short bf16x8 __attribute__((ext_vector_type(8)));
typedef float f32x4  __attribute__((ext_vector_type(4)));

__device__ __forceinline__ unsigned short f2bf(float f) {
    __hip_bfloat16 h = __float2bfloat16(f);
    return *(unsigned short*)&h;
}
__device__ __forceinline__ float bflo(unsigned int u) {
    return __uint_as_float(u << 16);
}
__device__ __forceinline__ float bfhi(unsigned int u) {
    return __uint_as_float(u & 0xffff0000u);
}

// ---------------------------------------------------------------------------
// Kernel 1 (v2): h = x @ W via bf16 MFMA — barrier-free persistent waves.
// Each wave: B for ALL 64 cols in regs (loaded once), grid-strides over
// 16-row tiles, A-frags loaded directly from global in MFMA layout.
// FUSED: attention logits (intra-quad shuffles) + cursor zeroing.
// A[m=lane&15][k=quad*8+j]; C: col=lane&15, row=quad*4+reg.
// ---------------------------------------------------------------------------
__global__ __launch_bounds__(256, 2) void gemm_mfma_kernel(
    const float* __restrict__ x, const float* __restrict__ W,
    const float* __restrict__ att_src, const float* __restrict__ att_dst,
    __hip_bfloat16* __restrict__ hb,
    float* __restrict__ a_src, float* __restrict__ a_dst,
    int* __restrict__ bcursor, int ncur, int ntiles)
{
    const int t    = threadIdx.x;
    const int gid  = blockIdx.x * 256 + t;
    const int lane = t & 63;
    const int m16  = lane & 15;
    const int quad = lane >> 4;
    const int gwave  = gid >> 6;
    const int nwaves = (gridDim.x * 256) >> 6;

    // fused cursor zeroing (grid covers ncur)
    if (gid < ncur) bcursor[gid] = 0;

    // B fragments for all 4 col-tiles x 4 k-blocks (64 VGPRs), loaded once
    bf16x8 B[4][4];
#pragma unroll
    for (int ct = 0; ct < 4; ++ct)
#pragma unroll
        for (int k0 = 0; k0 < 4; ++k0)
#pragma unroll
            for (int j = 0; j < 8; ++j)
                B[ct][k0][j] = (short)f2bf(
                    W[(k0 * 32 + quad * 8 + j) * HID_C + ct * 16 + m16]);

    float attS[4], attD[4];
#pragma unroll
    for (int ct = 0; ct < 4; ++ct) {
        attS[ct] = att_src[ct * 16 + m16];
        attD[ct] = att_dst[ct * 16 + m16];
    }

    for (int tile = gwave; tile < ntiles; tile += nwaves) {
        const int node0 = tile * 16;                  // N % 16 == 0
        const float* xr = x + (long)(node0 + m16) * IN_C + quad * 8;

        // A-frags: 8 dwordx4 direct global loads, convert to bf16
        bf16x8 A[4];
#pragma unroll
        for (int k0 = 0; k0 < 4; ++k0) {
            const float4 v0 = *(const float4*)(xr + k0 * 32);
            const float4 v1 = *(const float4*)(xr + k0 * 32 + 4);
            A[k0][0] = (short)f2bf(v0.x); A[k0][1] = (short)f2bf(v0.y);
            A[k0][2] = (short)f2bf(v0.z); A[k0][3] = (short)f2bf(v0.w);
            A[k0][4] = (short)f2bf(v1.x); A[k0][5] = (short)f2bf(v1.y);
            A[k0][6] = (short)f2bf(v1.z); A[k0][7] = (short)f2bf(v1.w);
        }

        f32x4 C[4];
#pragma unroll
        for (int ct = 0; ct < 4; ++ct) {
            C[ct] = (f32x4){0.f, 0.f, 0.f, 0.f};
#pragma unroll
            for (int k0 = 0; k0 < 4; ++k0)
                C[ct] = __builtin_amdgcn_mfma_f32_16x16x32_bf16(
                    A[k0], B[ct][k0], C[ct], 0, 0, 0);
        }

        // store hb (bf16): row = node0+quad*4+r, col = ct*16+m16
#pragma unroll
        for (int ct = 0; ct < 4; ++ct)
#pragma unroll
            for (int r = 0; r < 4; ++r)
                hb[(long)(node0 + quad * 4 + r) * HID_C + ct * 16 + m16] =
                    __float2bfloat16(C[ct][r]);

        // fused logits: per-row dot over cols; reduce over m16 (intra-quad)
        float ps[4] = {0.f, 0.f, 0.f, 0.f};
        float pd[4] = {0.f, 0.f, 0.f, 0.f};
#pragma unroll
        for (int ct = 0; ct < 4; ++ct)
#pragma unroll
            for (int r = 0; r < 4; ++r) {
                ps[r] = fmaf(C[ct][r], attS[ct], ps[r]);
                pd[r] = fmaf(C[ct][r], attD[ct], pd[r]);
            }
#pragma unroll
        for (int off = 1; off <= 8; off <<= 1) {
#pragma unroll
            for (int r = 0; r < 4; ++r) {
                ps[r] += __shfl_xor(ps[r], off, 64);
                pd[r] += __shfl_xor(pd[r], off, 64);
            }
        }
        if (m16 == 0) {
#pragma unroll
            for (int r = 0; r < 4; ++r) {
                a_src[node0 + quad * 4 + r] = ps[r];
                a_dst[node0 + quad * 4 + r] = pd[r];
            }
        }
    }
}

// ---------------------------------------------------------------------------
// Kernel 2 (bin level 1): edges -> 49 super-buckets (1024 dsts each).
// EPB1=1024 -> 782 blocks (~3/CU). Record = src16 | dloc10<<16 | sq6<<26, w.
// ---------------------------------------------------------------------------
__global__ __launch_bounds__(256) void bin1_kernel(
    const int* __restrict__ ei, int E,
    const float* __restrict__ a_src, const float* __restrict__ a_dst,
    int* __restrict__ bcur1, uint2* __restrict__ superbuf)
{
    __shared__ uint2 stage[EPB1];    // 8 KB
    __shared__ int excl[64];
    __shared__ int cur[64];
    __shared__ int gpos[64];

    const int t = threadIdx.x;
    const int base = blockIdx.x * EPB1;
    const int nedge = min(EPB1, E - base);

    if (t < 64) excl[t] = 0;
    __syncthreads();

    // histogram by super-bucket
    for (int i = t; i < nedge; i += 256)
        atomicAdd(&excl[ei[E + base + i] >> 10], 1);
    __syncthreads();

    // one-wave exclusive scan of 64 counters
    if (t < 64) {
        int c = excl[t], incl = c;
#pragma unroll
        for (int off = 1; off <= 32; off <<= 1) {
            int u = __shfl_up(incl, off, 64);
            if (t >= off) incl += u;
        }
        excl[t] = incl - c;
        cur[t]  = incl - c;
    }
    __syncthreads();

    // scatter into LDS stage grouped by super; compute w here
    for (int i = t; i < nedge; i += 256) {
        const int s = ei[base + i];
        const int d = ei[E + base + i];
        float e = a_src[s] + a_dst[d];
        e = (e >= 0.f) ? e : NEG_SLOPE * e;
        const float w = __expf(e);
        const int sq = d >> 10;
        const int pos = atomicAdd(&cur[sq], 1);
        stage[pos] = make_uint2((unsigned)s | ((unsigned)(d & 1023) << 16)
                                | ((unsigned)sq << 26),
                                __float_as_uint(w));
    }
    __syncthreads();

    // claim one contiguous global range per nonzero (block,super) group
    if (t < 64) {
        const int c = cur[t] - excl[t];
        gpos[t] = (c > 0) ? atomicAdd(&bcur1[t * CSTRIDE], c) : 0;
    }
    __syncthreads();

    // cooperative coalesced copy LDS -> global
    for (int i = t; i < nedge; i += 256) {
        const uint2 r = stage[i];
        const int sq = r.x >> 26;
        const int dp = gpos[sq] + (i - excl[sq]);
        if (dp < RCAP1) superbuf[(long)sq * RCAP1 + dp] = r;
    }
}

// ---------------------------------------------------------------------------
// Kernel 3 (bin level 2): super-buckets -> 64-dst regions.
// Output record = src16 | dloc6<<16, w  (agg's format).
// ---------------------------------------------------------------------------
__global__ __launch_bounds__(256) void bin2_kernel(
    const uint2* __restrict__ superbuf, const int* __restrict__ bcur1,
    int* __restrict__ bcur2, uint2* __restrict__ bucketbuf)
{
    __shared__ uint2 srt[EPB2];      // 16 KB
    __shared__ int cnt[16];
    __shared__ int rp[16];
    __shared__ int cur16[16];
    __shared__ int gpos[16];

    const int t    = threadIdx.x;
    const int sq   = blockIdx.x / PARTS;
    const int part = blockIdx.x % PARTS;
    const int tot  = min(bcur1[sq * CSTRIDE], RCAP1);
    const int beg  = part * EPB2;
    const int n    = min(EPB2, tot - beg);
    if (n <= 0) return;                       // block-uniform

    if (t < 16) cnt[t] = 0;
    __syncthreads();

    const uint2* src = superbuf + (long)sq * RCAP1 + beg;

    // pass 1: count per region-within-super (bits 22..25)
    for (int i = t; i < n; i += 256)
        atomicAdd(&cnt[(src[i].x >> 22) & 15], 1);
    __syncthreads();

    // tiny exclusive scan of 16 counters
    if (t == 0) {
        int run = 0;
#pragma unroll
        for (int k = 0; k < 16; ++k) { rp[k] = run; cur16[k] = run; run += cnt[k]; }
    }
    __syncthreads();

    // pass 2: regroup into LDS (second coalesced read, L2-hot)
    for (int i = t; i < n; i += 256) {
        const uint2 r = src[i];
        const int pos = atomicAdd(&cur16[(r.x >> 22) & 15], 1);
        srt[pos] = r;
    }
    __syncthreads();

    // claim global ranges per region
    if (t < 16) {
        const int c = cnt[t];
        const int q2 = sq * 16 + t;
        gpos[t] = (c > 0) ? atomicAdd(&bcur2[q2 * CSTRIDE], c) : 0;
    }
    __syncthreads();

    // coalesced copy out with format conversion
    for (int i = t; i < n; i += 256) {
        const uint2 r = srt[i];
        const int idx = (r.x >> 22) & 15;
        const int dp  = gpos[idx] + (i - rp[idx]);
        const int q2  = sq * 16 + idx;
        const unsigned nx = (r.x & 0xFFFFu) | (((r.x >> 16) & 63u) << 16);
        if (dp < RCAP) bucketbuf[(long)q2 * RCAP + dp] = make_uint2(nx, r.y);
    }
}

// ---------------------------------------------------------------------------
// Kernel 4: per-region aggregation + register epilogue (R9/R11 layout).
// ---------------------------------------------------------------------------
__global__ __launch_bounds__(512) void bucket_agg_kernel(
    const uint2* __restrict__ bucketbuf, const int* __restrict__ bcursor,
    const __hip_bfloat16* __restrict__ hb,
    const float* __restrict__ a_src, const float* __restrict__ a_dst,
    const float* __restrict__ bias_conv,
    const float* __restrict__ W_lin, const float* __restrict__ b_lin,
    float* __restrict__ out, int n_nodes)
{
    __shared__ uint2 srtL[RCAP];        // 12.3 KB
    __shared__ int cntd[BUCKETW];
    __shared__ int rp[BUCKETW + 1];
    __shared__ int curd[BUCKETW];

    const int t  = threadIdx.x;
    const int q  = blockIdx.x;
    const int d0 = q * BUCKETW;
    const int dmax = min(BUCKETW, n_nodes - d0);
    const int tot  = min(bcursor[q * CSTRIDE], RCAP);
    const int wv = t >> 6, lane = t & 63, g8 = lane >> 3, l = lane & 7;

    if (t < BUCKETW) cntd[t] = 0;
    __syncthreads();

    const uint2* gsrc = bucketbuf + (long)q * RCAP;

    // pass 1: count per dloc
    for (int i = t; i < tot; i += 512)
        atomicAdd(&cntd[(gsrc[i].x >> 16) & 63], 1);
    __syncthreads();

    // one-wave scan of 64 counters
    if (t < 64) {
        int c = cntd[t], incl = c;
#pragma unroll
        for (int off = 1; off <= 32; off <<= 1) {
            int u = __shfl_up(incl, off, 64);
            if (t >= off) incl += u;
        }
        rp[t] = incl - c;
        curd[t] = incl - c;
        if (t == 63) rp[64] = incl;
    }
    __syncthreads();

    // pass 2: scatter into sorted LDS order
    for (int i = t; i < tot; i += 512) {
        const uint2 r = gsrc[i];
        const int pos = atomicAdd(&curd[(r.x >> 16) & 63], 1);
        srtL[pos] = r;
    }
    __syncthreads();

    // per-lane epilogue constants
    float Wr[8][4];
#pragma unroll
    for (int kc = 0; kc < 8; ++kc)
#pragma unroll
        for (int kj = 0; kj < 4; ++kj)
            Wr[kc][kj] = W_lin[(l * 8 + kc) * OUT_C + g8 * 4 + kj];
    float biasR[8];
#pragma unroll
    for (int kc = 0; kc < 8; ++kc) biasR[kc] = bias_conv[l * 8 + kc];
    float blinR[4];
#pragma unroll
    for (int kj = 0; kj < 4; ++kj) blinR[kj] = b_lin[g8 * 4 + kj];

    const unsigned short* hbs = (const unsigned short*)hb;

    for (int dloc = wv; dloc < dmax; dloc += 8) {
        const int d = d0 + dloc;
        float A[8] = {0.f,0.f,0.f,0.f,0.f,0.f,0.f,0.f};
        float den = 0.f;
        if (g8 == 0) {        // self-loop on slot 0
            float e = a_src[d] + a_dst[d];
            e = (e >= 0.f) ? e : NEG_SLOPE * e;
            const float ws = __expf(e);
            const uint4 hv = *(const uint4*)(hbs + (long)d * HID_C + l * 8);
            den = ws;
            A[0] = ws * bflo(hv.x); A[1] = ws * bfhi(hv.x);
            A[2] = ws * bflo(hv.y); A[3] = ws * bfhi(hv.y);
            A[4] = ws * bflo(hv.z); A[5] = ws * bfhi(hv.z);
            A[6] = ws * bflo(hv.w); A[7] = ws * bfhi(hv.w);
        }
        const int beg = rp[dloc], fin = rp[dloc + 1];
        for (int j = beg + g8; j < fin; j += 16) {
            const int  j1   = j + 8;
            const bool has1 = j1 < fin;
            const uint2 r0 = srtL[j];
            const uint2 r1 = srtL[has1 ? j1 : j];
            const int   s0 = r0.x & 0xFFFF;
            const int   s1 = r1.x & 0xFFFF;
            const float w0 = __uint_as_float(r0.y);
            const float w1 = has1 ? __uint_as_float(r1.y) : 0.f;
            const uint4 h0 = *(const uint4*)(hbs + (long)s0 * HID_C + l * 8);
            const uint4 h1 = *(const uint4*)(hbs + (long)s1 * HID_C + l * 8);
            den += w0 + w1;
            A[0] = fmaf(w0, bflo(h0.x), A[0]); A[1] = fmaf(w0, bfhi(h0.x), A[1]);
            A[2] = fmaf(w0, bflo(h0.y), A[2]); A[3] = fmaf(w0, bfhi(h0.y), A[3]);
            A[4] = fmaf(w0, bflo(h0.z), A[4]); A[5] = fmaf(w0, bfhi(h0.z), A[5]);
            A[6] = fmaf(w0, bflo(h0.w), A[6]); A[7] = fmaf(w0, bfhi(h0.w), A[7]);
            A[0] = fmaf(w1, bflo(h1.x), A[0]); A[1] = fmaf(w1, bfhi(h1.x), A[1]);
            A[2] = fmaf(w1, bflo(h1.y), A[2]); A[3] = fmaf(w1, bfhi(h1.y), A[3]);
            A[4] = fmaf(w1, bflo(h1.z), A[4]); A[5] = fmaf(w1, bfhi(h1.z), A[5]);
            A[6] = fmaf(w1, bflo(h1.w), A[6]); A[7] = fmaf(w1, bfhi(h1.w), A[7]);
        }
#pragma unroll
        for (int off = 8; off <= 32; off <<= 1) {
#pragma unroll
            for (int k = 0; k < 8; ++k) A[k] += __shfl_xor(A[k], off, 64);
            den += __shfl_xor(den, off, 64);
        }
        const float rd = 1.0f / (den + 1e-16f);
        float p0 = 0.f, p1 = 0.f, p2 = 0.f, p3 = 0.f;
#pragma unroll
        for (int kc = 0; kc < 8; ++kc) {
            float vv = fmaf(A[kc], rd, biasR[kc]);
            vv = vv > 0.f ? vv : 0.f;
            p0 = fmaf(vv, Wr[kc][0], p0);
            p1 = fmaf(vv, Wr[kc][1], p1);
            p2 = fmaf(vv, Wr[kc][2], p2);
            p3 = fmaf(vv, Wr[kc][3], p3);
        }
#pragma unroll
        for (int off = 1; off <= 4; off <<= 1) {
            p0 += __shfl_xor(p0, off, 64);
            p1 += __shfl_xor(p1, off, 64);
            p2 += __shfl_xor(p2, off, 64);
            p3 += __shfl_xor(p3, off, 64);
        }
        if (l == 0) {
            float4 o = make_float4(p0 + blinR[0], p1 + blinR[1],
                                   p2 + blinR[2], p3 + blinR[3]);
            *(float4*)(out + (long)d * OUT_C + g8 * 4) = o;
        }
    }
}

// ---------------------------------------------------------------------------
extern "C" void kernel_launch(void* const* d_in, const int* in_sizes, int n_in,
                              void* d_out, int out_size, void* d_ws, size_t ws_size,
                              hipStream_t stream) {
    const float* x         = (const float*)d_in[0];
    const int*   ei        = (const int*)d_in[1];
    const float* W         = (const float*)d_in[2];
    const float* att_src   = (const float*)d_in[3];
    const float* att_dst   = (const float*)d_in[4];
    const float* bias_conv = (const float*)d_in[5];
    const float* W_lin     = (const float*)d_in[6];
    const float* b_lin     = (const float*)d_in[7];
    float*       out       = (float*)d_out;

    const int n_nodes = in_sizes[0] / IN_C;              // 50000
    const int E       = in_sizes[1] / 2;                 // 800000
    const int B1   = (E + EPB1 - 1) / EPB1;              // 782 bin1 blocks
    const int Q    = (n_nodes + BUCKETW - 1) / BUCKETW;  // 782 regions
    const int NSUP = (n_nodes + SUPW - 1) / SUPW;        // 49 supers
    const int ntiles = (n_nodes + 15) / 16;              // 3125 (exact)

    // workspace layout
    __hip_bfloat16* hb = (__hip_bfloat16*)d_ws;              // N*64 bf16 (6.4MB)
    float* a_src   = (float*)(hb + (long)n_nodes * HID_C);   // N f
    float* a_dst   = a_src + n_nodes;                        // N f
    int*   bcur1   = (int*)(a_dst + n_nodes);                // NSUP*CSTRIDE
    int*   bcur2   = bcur1 + NSUP * CSTRIDE;                 // Q*CSTRIDE
    uint2* superbuf  = (uint2*)(bcur2 + (long)Q * CSTRIDE);  // NSUP*RCAP1*8B (7.2MB)
    uint2* bucketbuf = superbuf + (long)NSUP * RCAP1;        // Q*RCAP*8B (9.6MB)

    const int ncur = (NSUP + Q) * CSTRIDE;

    // 1) h = x @ W (bf16 MFMA, barrier-free) + fused logits + cursor zeroing
    gemm_mfma_kernel<<<512, 256, 0, stream>>>(
        x, W, att_src, att_dst, hb, a_src, a_dst,
        bcur1, ncur, ntiles);

    // 2) bin level 1: edges -> super-buckets (computes per-edge w)
    bin1_kernel<<<B1, 256, 0, stream>>>(
        ei, E, a_src, a_dst, bcur1, superbuf);

    // 3) bin level 2: super-buckets -> regions
    bin2_kernel<<<NSUP * PARTS, 256, 0, stream>>>(
        superbuf, bcur1, bcur2, bucketbuf);

    // 4) per-region aggregation + register epilogue
    bucket_agg_kernel<<<Q, 512, 0, stream>>>(
        bucketbuf, bcur2, hb, a_src, a_dst,
        bias_conv, W_lin, b_lin, out, n_nodes);
}